// Round 17
// baseline (193.642 us; speedup 1.0000x reference)
//
#include <hip/hip_runtime.h>
#include <hip/hip_bf16.h>

typedef __bf16 bf16;
typedef __attribute__((ext_vector_type(8))) __bf16 bf16x8;
typedef __attribute__((ext_vector_type(4))) __bf16 bf16x4;
typedef __attribute__((ext_vector_type(4))) float f32x4;
typedef __attribute__((ext_vector_type(16))) float f32x16;
typedef __attribute__((ext_vector_type(4))) unsigned int u32x4;

#define DIMD  1024
#define SEQ   2048
#define BATCH 2
#define HEADS 16
#define INNER 1024
#define QKVN  3072   // q(1024) | k(1024) | v(1024)
#define ROWS  (BATCH*SEQ)  // 4096
#define LOG2E 1.44269504f

// ---------------- LayerNorm over the SEQUENCE axis (per (b,d)) ----------------
__global__ void ln_partial(const float* __restrict__ x,
                           float* __restrict__ psum, float* __restrict__ psq) {
    const int nc = blockIdx.x;   // 0..63
    const int b  = blockIdx.y;   // 0..1
    const int t  = threadIdx.x;  // 0..255
    const float* xp = x + ((size_t)b*SEQ + (size_t)nc*32)*DIMD;
    float s0=0,s1=0,s2=0,s3=0,q0=0,q1=0,q2=0,q3=0;
    for (int r=0; r<32; ++r) {
        const float* row = xp + (size_t)r*DIMD;
        float v0=row[t], v1=row[t+256], v2=row[t+512], v3=row[t+768];
        s0+=v0; q0+=v0*v0; s1+=v1; q1+=v1*v1;
        s2+=v2; q2+=v2*v2; s3+=v3; q3+=v3*v3;
    }
    float* ps = psum + ((size_t)b*64 + nc)*DIMD;
    float* pq = psq  + ((size_t)b*64 + nc)*DIMD;
    ps[t]=s0; ps[t+256]=s1; ps[t+512]=s2; ps[t+768]=s3;
    pq[t]=q0; pq[t+256]=q1; pq[t+512]=q2; pq[t+768]=q3;
}

__global__ void ln_finalize(const float* __restrict__ psum, const float* __restrict__ psq,
                            const float* __restrict__ g,
                            float* __restrict__ scale, float* __restrict__ shift) {
    const int d = blockIdx.x*256 + threadIdx.x;  // 0..1023
    const int b = blockIdx.y;
    float s=0.f, q=0.f;
    for (int nc=0; nc<64; ++nc) {
        s += psum[((size_t)b*64+nc)*DIMD + d];
        q += psq [((size_t)b*64+nc)*DIMD + d];
    }
    const float inv_n = 1.f/(float)SEQ;
    float mean = s*inv_n;
    float var  = q*inv_n - mean*mean;
    var = fmaxf(var, 1e-5f);
    scale[b*DIMD+d] = g[d]*rsqrtf(var);
    shift[b*DIMD+d] = mean;
}

__global__ void ln_apply(const float* __restrict__ x,
                         const float* __restrict__ scale, const float* __restrict__ shift,
                         bf16* __restrict__ xn) {
    size_t idx = ((size_t)blockIdx.x*256 + threadIdx.x)*4;
    int b = (int)(idx >> 21);          // SEQ*DIMD = 2^21
    int d = (int)(idx & (DIMD-1));
    f32x4 v  = *reinterpret_cast<const f32x4*>(x + idx);
    f32x4 sc = *reinterpret_cast<const f32x4*>(scale + (size_t)b*DIMD + d);
    f32x4 sh = *reinterpret_cast<const f32x4*>(shift + (size_t)b*DIMD + d);
    bf16x4 o;
    o.x = (bf16)((v.x - sh.x)*sc.x);
    o.y = (bf16)((v.y - sh.y)*sc.y);
    o.z = (bf16)((v.z - sh.z)*sc.z);
    o.w = (bf16)((v.w - sh.w)*sc.w);
    *reinterpret_cast<bf16x4*>(xn + idx) = o;
}

// ---------------- merged weight casts (Wq*qs, Wkv, Wo) ----------------
__global__ void castk_all(const float* __restrict__ Wq, const float* __restrict__ Wkv,
                          const float* __restrict__ Wo,
                          bf16* __restrict__ wqkv, bf16* __restrict__ wo, float qs) {
    int i = (blockIdx.x*256 + threadIdx.x)*4;   // 0 .. 4M-4
    f32x4 v; bf16* dst;
    if (i < 1048576)      { v = *reinterpret_cast<const f32x4*>(Wq + i);
                            v.x*=qs; v.y*=qs; v.z*=qs; v.w*=qs; dst = wqkv + i; }
    else if (i < 3145728) { v = *reinterpret_cast<const f32x4*>(Wkv + (i-1048576));
                            dst = wqkv + i; }
    else                  { v = *reinterpret_cast<const f32x4*>(Wo + (i-3145728));
                            dst = wo + (i-3145728); }
    bf16x4 o; o.x=(bf16)v.x; o.y=(bf16)v.y; o.z=(bf16)v.z; o.w=(bf16)v.w;
    *reinterpret_cast<bf16x4*>(dst) = o;
}

// ---------------- async global->LDS (16B, m97 pattern) ----------------
__device__ __forceinline__ void gload16(const void* g, void* l) {
    __builtin_amdgcn_global_load_lds(
        (const __attribute__((address_space(1))) unsigned int*)g,
        (__attribute__((address_space(3))) unsigned int*)l,
        16, 0, 0);
}

// ---------------- bt-GEMM (m97 structure): C[m][n] = sum_k A[m][k]*B[n][k] ----
__device__ inline void store_out(float* p, float v) { *p = v; }
__device__ inline void store_out(bf16*  p, float v) { *p = (bf16)v; }

template <typename OT>
__global__ __launch_bounds__(256, 2)
void gemm_bt(const bf16* __restrict__ A, const bf16* __restrict__ B,
             OT* __restrict__ C, int M, int N, int K) {
    __shared__ bf16 As[128*64];
    __shared__ bf16 Bs[128*64];
    const int t = threadIdx.x;
    const int wave = t >> 6, lane = t & 63;
    const int wr = wave >> 1, wc = wave & 1;
    const int m0 = blockIdx.y*128, n0 = blockIdx.x*128;
    const int lr = lane & 15, lg = lane >> 4;
    const int srow = wave*32 + (lane>>3);   // +8*i
    const int scol = (lane&7)*8;            // bf16 elems (16B)

    f32x4 acc[4][4];
    #pragma unroll
    for (int i=0;i<4;++i)
        #pragma unroll
        for (int j=0;j<4;++j) acc[i][j] = (f32x4){0.f,0.f,0.f,0.f};

    for (int k0=0; k0<K; k0+=64) {
        #pragma unroll
        for (int i=0;i<4;++i) {
            gload16(A + (size_t)(m0+srow+8*i)*K + k0 + scol, As + (srow+8*i)*64 + scol);
            gload16(B + (size_t)(n0+srow+8*i)*K + k0 + scol, Bs + (srow+8*i)*64 + scol);
        }
        __syncthreads();
        #pragma unroll
        for (int kk=0; kk<2; ++kk) {
            bf16x8 a[4], b[4];
            #pragma unroll
            for (int mi=0;mi<4;++mi)
                a[mi] = *reinterpret_cast<const bf16x8*>(As + (wr*64+mi*16+lr)*64 + kk*32+lg*8);
            #pragma unroll
            for (int ni=0;ni<4;++ni)
                b[ni] = *reinterpret_cast<const bf16x8*>(Bs + (wc*64+ni*16+lr)*64 + kk*32+lg*8);
            #pragma unroll
            for (int mi=0;mi<4;++mi)
                #pragma unroll
                for (int ni=0;ni<4;++ni)
                    acc[mi][ni] = __builtin_amdgcn_mfma_f32_16x16x32_bf16(a[mi], b[ni], acc[mi][ni], 0, 0, 0);
        }
        __syncthreads();
    }
    #pragma unroll
    for (int mi=0;mi<4;++mi)
        #pragma unroll
        for (int ni=0;ni<4;++ni)
            #pragma unroll
            for (int r=0;r<4;++r) {
                int row = m0 + wr*64 + mi*16 + lg*4 + r;
                int col = n0 + wc*64 + ni*16 + lr;
                store_out(&C[(size_t)row*N + col], acc[mi][ni][r]);
            }
}

// ---------------- V transpose: qkv V part -> vT[b][h][d][n] ----------------
__global__ __launch_bounds__(256)
void transpose_v(const bf16* __restrict__ qkv, bf16* __restrict__ vT) {
    __shared__ bf16 tile[64][72];
    const int nt = blockIdx.x, h = blockIdx.y, b = blockIdx.z;
    const int t = threadIdx.x;
    const bf16* src = qkv + ((size_t)(b*SEQ + nt*64))*QKVN + 2*INNER + h*64;
    #pragma unroll
    for (int i=0;i<2;++i) {
        int c = t + 256*i, row = c>>3, col = (c&7)*8;
        *reinterpret_cast<bf16x8*>(&tile[row][col]) =
            *reinterpret_cast<const bf16x8*>(src + (size_t)row*QKVN + col);
    }
    __syncthreads();
    bf16* dst = vT + ((size_t)(b*HEADS + h))*64*SEQ + nt*64;
    #pragma unroll
    for (int i=0;i<2;++i) {
        int c = t + 256*i, d = c>>3, n0 = (c&7)*8;
        bf16x8 v;
        #pragma unroll
        for (int j=0;j<8;++j) v[j] = tile[n0+j][d];
        *reinterpret_cast<bf16x8*>(dst + (size_t)d*SEQ + n0) = v;
    }
}

// ---------------- fused flash attention: DMA staging (global_load_lds) -------
// Block = (qt, h), 512 threads = 8 waves (waves 0-3 batch 0, 4-7 batch 1).
// K/V/bias ALL staged via global_load_lds width-16: pre-swizzled SOURCE +
// linear LDS dest (same LDS[row][x] = src-granule x^(row&7)/(row&15) mapping
// as the verified R16 read side; rule-21 involution). No staging VGPRs, no
// ds_writes, no VMEM->VGPR return traffic. Pipeline: issue tile T+1's 8 DMA
// loads at iter-T top, drain vmcnt(0) at the iter barrier (m97 pattern).
// 32x32 MFMA, in-reg P, exp2 softmax w/ defer-max.

__device__ __forceinline__ unsigned pk2(float a, float b) {
    union { bf16 h[2]; unsigned u; } x;
    x.h[0] = (bf16)a; x.h[1] = (bf16)b;
    return x.u;
}

#define ATTN_BARRIER_VM()                                                \
    __builtin_amdgcn_sched_barrier(0);                                   \
    asm volatile("s_waitcnt vmcnt(0) lgkmcnt(0)" ::: "memory");          \
    __builtin_amdgcn_s_barrier();                                        \
    __builtin_amdgcn_sched_barrier(0)

#define STAGE(BUF, TT)                                                           \
  {                                                                              \
    gload16(kA + (size_t)(TT)*64*QKVN, &Ks[0][BUF][t*8]);                        \
    gload16(kB + (size_t)(TT)*64*QKVN, &Ks[1][BUF][t*8]);                        \
    gload16(vA + (TT)*64,              &VTs[0][BUF][t*8]);                       \
    gload16(vB + (TT)*64,              &VTs[1][BUF][t*8]);                       \
    _Pragma("unroll")                                                            \
    for (int i_=0;i_<4;++i_)                                                     \
        gload16(bptr + (size_t)(32*i_)*SEQ + (TT)*64, &BsL[BUF][t*4 + i_*2048]); \
  }

#define ATTN_ITER(CUR, T)                                                          \
  {                                                                                \
    /* issue DMA staging for tile T+1 -> buf CUR^1 (drained at this iter's bar) */ \
    if ((T)+1 < 32) STAGE((CUR)^1, (T)+1);                                         \
    /* QK(T): S^T = mfma(K, Q), two 32-kv blocks */                                \
    f32x16 p0 = (f32x16)(0.0f), p1 = (f32x16)(0.0f);                               \
    __builtin_amdgcn_s_setprio(1);                                                 \
    _Pragma("unroll")                                                              \
    for (int s=0;s<4;++s) {                                                        \
      bf16x8 kf0 = *reinterpret_cast<const bf16x8*>(&myK[(CUR)*4096 + koff[0][s]]); \
      p0 = __builtin_amdgcn_mfma_f32_32x32x16_bf16(kf0, qf[s], p0, 0,0,0);         \
      bf16x8 kf1 = *reinterpret_cast<const bf16x8*>(&myK[(CUR)*4096 + koff[1][s]]); \
      p1 = __builtin_amdgcn_mfma_f32_32x32x16_bf16(kf1, qf[s], p1, 0,0,0);         \
    }                                                                              \
    __builtin_amdgcn_s_setprio(0);                                                 \
    /* bias(T) from block-shared LDS (2-way max, free) */                          \
    f32x4 bb0[4], bb1[4];                                                          \
    _Pragma("unroll")                                                              \
    for (int rr=0;rr<4;++rr) {                                                     \
      bb0[rr] = *reinterpret_cast<const f32x4*>(&BsL[CUR][brd[0][rr]]);            \
      bb1[rr] = *reinterpret_cast<const f32x4*>(&BsL[CUR][brd[1][rr]]);            \
    }                                                                              \
    /* softmax: bias add (exp2 domain), in-lane tree, cross-half combine */        \
    float v0[16], v1[16];                                                          \
    _Pragma("unroll")                                                              \
    for (int r=0;r<16;++r) {                                                       \
      v0[r] = __builtin_fmaf(bb0[r>>2][r&3], LOG2E, p0[r]);                        \
      v1[r] = __builtin_fmaf(bb1[r>>2][r&3], LOG2E, p1[r]);                        \
    }                                                                              \
    float mx[8];                                                                   \
    _Pragma("unroll")                                                              \
    for (int i=0;i<8;++i)                                                          \
      mx[i] = fmaxf(fmaxf(v0[i], v0[i+8]), fmaxf(v1[i], v1[i+8]));                 \
    _Pragma("unroll")                                                              \
    for (int i=0;i<4;++i) mx[i] = fmaxf(mx[i], mx[i+4]);                           \
    float vmax = fmaxf(fmaxf(mx[0],mx[2]), fmaxf(mx[1],mx[3]));                    \
    vmax = fmaxf(vmax, __shfl_xor(vmax, 32));                                      \
    if (!__all(vmax <= m + 11.5f)) {                                               \
      float mnew = fmaxf(m, vmax);                                                 \
      float sc = __builtin_amdgcn_exp2f(m - mnew);                                 \
      m = mnew; l *= sc;                                                           \
      _Pragma("unroll")                                                            \
      for (int r=0;r<16;++r) {                                                     \
        float scr = __shfl(sc, (r&3)+8*(r>>2)+4*hi);                               \
        accO0[r] *= scr; accO1[r] *= scr;                                          \
      }                                                                            \
    }                                                                              \
    float e0[16], e1[16];                                                          \
    _Pragma("unroll")                                                              \
    for (int r=0;r<16;++r) {                                                       \
      e0[r] = __builtin_amdgcn_exp2f(v0[r] - m);                                   \
      e1[r] = __builtin_amdgcn_exp2f(v1[r] - m);                                   \
    }                                                                              \
    float sm[8];                                                                   \
    _Pragma("unroll")                                                              \
    for (int i=0;i<8;++i) sm[i] = (e0[i]+e0[i+8]) + (e1[i]+e1[i+8]);               \
    _Pragma("unroll")                                                              \
    for (int i=0;i<4;++i) sm[i] += sm[i+4];                                        \
    float rsum = (sm[0]+sm[2]) + (sm[1]+sm[3]);                                    \
    rsum += __shfl_xor(rsum, 32);                                                  \
    l += rsum;                                                                     \
    /* pack P to bf16 words: W[B2][rr][h] = kv pair (32B2+8rr+4hi+2h, +1) */       \
    unsigned W0[4][2], W1[4][2];                                                   \
    _Pragma("unroll")                                                              \
    for (int rr=0;rr<4;++rr) {                                                     \
      W0[rr][0] = pk2(e0[4*rr+0], e0[4*rr+1]);                                     \
      W0[rr][1] = pk2(e0[4*rr+2], e0[4*rr+3]);                                     \
      W1[rr][0] = pk2(e1[4*rr+0], e1[4*rr+1]);                                     \
      W1[rr][1] = pk2(e1[4*rr+2], e1[4*rr+3]);                                     \
    }                                                                              \
    /* build PV A-frags pa[s4]: kv = 16*s4 + 8*hi + e */                           \
    bf16x8 pa[4];                                                                  \
    _Pragma("unroll")                                                              \
    for (int s4=0;s4<4;++s4) {                                                     \
      unsigned u[4];                                                               \
      _Pragma("unroll")                                                            \
      for (int hh=0;hh<2;++hh) {                                                   \
        unsigned a0 = (s4>>1) ? W1[2*(s4&1)  ][hh] : W0[2*(s4&1)  ][hh];           \
        unsigned a1 = (s4>>1) ? W1[2*(s4&1)+1][hh] : W0[2*(s4&1)+1][hh];           \
        unsigned X = hi ? a0 : a1;                                                 \
        unsigned R = (unsigned)__shfl_xor((int)X, 32);                             \
        u[hh]   = hi ? R  : a0;                                                    \
        u[2+hh] = hi ? a1 : R;                                                     \
      }                                                                            \
      u32x4 uv = {u[0], u[1], u[2], u[3]};                                         \
      pa[s4] = __builtin_bit_cast(bf16x8, uv);                                     \
    }                                                                              \
    /* PV(T) */                                                                    \
    __builtin_amdgcn_s_setprio(1);                                                 \
    _Pragma("unroll")                                                              \
    for (int s4=0;s4<4;++s4) {                                                     \
      bf16x8 vfa = *reinterpret_cast<const bf16x8*>(&myV[(CUR)*4096 + voff[0][s4]]); \
      accO0 = __builtin_amdgcn_mfma_f32_32x32x16_bf16(pa[s4], vfa, accO0, 0,0,0);  \
      bf16x8 vfb = *reinterpret_cast<const bf16x8*>(&myV[(CUR)*4096 + voff[1][s4]]); \
      accO1 = __builtin_amdgcn_mfma_f32_32x32x16_bf16(pa[s4], vfb, accO1, 0,0,0);  \
    }                                                                              \
    __builtin_amdgcn_s_setprio(0);                                                 \
    ATTN_BARRIER_VM();                                                             \
  }

__global__ __launch_bounds__(512, 1)
void attn_kernel(const bf16* __restrict__ qkv, const bf16* __restrict__ vTg,
                 const float* __restrict__ bias, bf16* __restrict__ oh) {
    __shared__ bf16 Ks[2][2][64*64];    // [batch][buf] 8KB tiles
    __shared__ bf16 VTs[2][2][64*64];   // [batch][buf]
    __shared__ float BsL[2][128*64];    // [buf][q 0..127][kv 0..63] swizzled (64KB)

    const int qt = blockIdx.x, h = blockIdx.y;
    const int t = threadIdx.x;
    const int w = t >> 6, lane = t & 63;
    const int wb = w >> 2;               // batch of this wave
    const int wq = w & 3;                // q-subtile within batch
    const int ql = lane & 31, hi = lane >> 5;
    const int q0 = qt*128;

    // swizzled LDS read offsets for K/V (elements), + CUR*4096
    // LDS[row][x] holds source granule x ^ (row&7)  (16B granules)
    int koff[2][4], voff[2][4];
    #pragma unroll
    for (int B2=0;B2<2;++B2)
        #pragma unroll
        for (int s=0;s<4;++s) {
            koff[B2][s] = (32*B2+ql)*64 + (((2*s+hi) ^ (ql&7))*8);
            voff[B2][s] = (32*B2+ql)*64 + (((2*s+hi) ^ (ql&7))*8);
        }
    bf16* myK = (bf16*)Ks[wb];
    bf16* myV = (bf16*)VTs[wb];

    // bias read offsets: LDS[row][x] holds source granule x ^ (row&15) (16B gran)
    int brd[2][4];
    #pragma unroll
    for (int B2=0;B2<2;++B2)
        #pragma unroll
        for (int rr=0;rr<4;++rr)
            brd[B2][rr] = (wq*32+ql)*64 + (((8*B2+2*rr+hi) ^ (ql&15))*4);

    // ---- DMA staging source bases (pre-swizzled; LDS dest is linear t*16B) ----
    // K/V: thread t -> LDS row t>>3, granule t&7; source granule (t&7)^((t>>3)&7)
    const int swz8k = (((t&7) ^ ((t>>3)&7))*8);
    const bf16* kbase0 = qkv + INNER + h*64;
    const bf16* kbase1 = qkv + (size_t)SEQ*QKVN + INNER + h*64;
    const bf16* vtb0   = vTg + (size_t)h*64*SEQ;
    const bf16* vtb1   = vTg + (size_t)(HEADS + h)*64*SEQ;
    const bf16* kA = kbase0 + (size_t)(t>>3)*QKVN + swz8k;
    const bf16* kB = kbase1 + (size_t)(t>>3)*QKVN + swz8k;
    const bf16* vA = vtb0 + (size_t)(t>>3)*SEQ + swz8k;
    const bf16* vB = vtb1 + (size_t)(t>>3)*SEQ + swz8k;
    // bias: round i -> LDS row (t>>4)+32i, granule t&15; source granule (t&15)^((t>>4)&15)
    const float* bptr = bias + ((size_t)h*SEQ + (size_t)(q0 + (t>>4)))*SEQ
                              + (((t&15) ^ ((t>>4)&15))*4);

    // Q fragments (prescaled 0.125*log2e): row q0+wq*32+ql, d = 16s+8hi+e
    const bf16* qrow = qkv + ((size_t)(wb*SEQ + q0 + wq*32 + ql))*QKVN + h*64 + hi*8;
    bf16x8 qf[4];
    #pragma unroll
    for (int s=0;s<4;++s)
        qf[s] = *reinterpret_cast<const bf16x8*>(qrow + 16*s);

    // prologue: DMA tile 0 -> buf 0, drain, go
    STAGE(0, 0);
    ATTN_BARRIER_VM();

    float m = -__builtin_inff();
    float l = 0.f;
    f32x16 accO0 = (f32x16)(0.0f), accO1 = (f32x16)(0.0f);

    for (int t2 = 0; t2 < 32; t2 += 2) {
        ATTN_ITER(0, t2);
        ATTN_ITER(1, t2+1);
    }

    // epilogue: O /= l ; accO{dt}[r]: q = (r&3)+8*(r>>2)+4*hi, d = dt*32+ql
    float linv = 1.f/l;
    bf16* ob = oh + ((size_t)(wb*SEQ + q0 + wq*32))*INNER + h*64 + ql;
    #pragma unroll
    for (int r=0;r<16;++r) {
        int qoff = (r&3) + 8*(r>>2) + 4*hi;
        float li = __shfl(linv, qoff);
        ob[(size_t)qoff*INNER]      = (bf16)(accO0[r]*li);
        ob[(size_t)qoff*INNER + 32] = (bf16)(accO1[r]*li);
    }
}

// ---------------- host launcher ----------------
extern "C" void kernel_launch(void* const* d_in, const int* in_sizes, int n_in,
                              void* d_out, int out_size, void* d_ws, size_t ws_size,
                              hipStream_t stream) {
    const float* x    = (const float*)d_in[0];
    const float* bias = (const float*)d_in[1];
    const float* g    = (const float*)d_in[2];
    const float* Wq   = (const float*)d_in[3];
    const float* Wkv  = (const float*)d_in[4];
    const float* Wo   = (const float*)d_in[5];
    float* out = (float*)d_out;

    char* ws = (char*)d_ws;
    bf16*  xn    = (bf16*)(ws);                       //  8,388,608 B (dead after QKV gemm)
    bf16*  vT    = (bf16*)(ws);                       //  overlays xn
    bf16*  wqkv  = (bf16*)(ws + 8388608);             //  6,291,456 B
    bf16*  wo    = (bf16*)(ws + 14680064);            //  2,097,152 B
    bf16*  qkv   = (bf16*)(ws + 16777216);            // 25,165,824 B
    bf16*  oh    = (bf16*)(ws + 41943040);            //  8,388,608 B
    float* psum  = (float*)(ws + 50331648);           //    524,288 B
    float* psq   = (float*)(ws + 50855936);           //    524,288 B
    float* scale = (float*)(ws + 51380224);           //      8,192 B
    float* shift = (float*)(ws + 51388416);           //      8,192 B

    ln_partial <<<dim3(64,2), 256, 0, stream>>>(x, psum, psq);
    ln_finalize<<<dim3(4,2),  256, 0, stream>>>(psum, psq, g, scale, shift);
    ln_apply   <<<dim3(4096), 256, 0, stream>>>(x, scale, shift, xn);

    // merged weight casts: Wq prescaled by 0.125*log2e, Wkv, Wo
    castk_all<<<dim3(4096), 256, 0, stream>>>(Wq, Wkv, Wo, wqkv, wo, 0.125f*LOG2E);

    // QKV = xn @ [Wq;Wkv]^T : M=4096, N=3072, K=1024
    gemm_bt<bf16><<<dim3(24,32), 256, 0, stream>>>(xn, wqkv, qkv, ROWS, QKVN, DIMD);

    // V -> V^T (per (b,h): [2048 n][64 d] -> [64 d][2048 n]); vT overlays dead xn
    transpose_v<<<dim3(32,16,2), 256, 0, stream>>>(qkv, vT);

    // fused attention (dual-batch, DMA-staged K/V/bias) -> oh
    attn_kernel<<<dim3(16,16), 512, 0, stream>>>(qkv, vT, bias, oh);

    // final = oh @ Wo^T : M=4096, N=1024, K=1024, fp32 out
    gemm_bt<float><<<dim3(8,32), 256, 0, stream>>>(oh, wo, out, ROWS, INNER, INNER);
}

// Round 18
// 186.945 us; speedup vs baseline: 1.0358x; 1.0358x over previous
//
#include <hip/hip_runtime.h>
#include <hip/hip_bf16.h>

typedef __bf16 bf16;
typedef __attribute__((ext_vector_type(8))) __bf16 bf16x8;
typedef __attribute__((ext_vector_type(4))) __bf16 bf16x4;
typedef __attribute__((ext_vector_type(4))) float f32x4;
typedef __attribute__((ext_vector_type(16))) float f32x16;
typedef __attribute__((ext_vector_type(4))) unsigned int u32x4;

#define DIMD  1024
#define SEQ   2048
#define BATCH 2
#define HEADS 16
#define INNER 1024
#define QKVN  3072   // q(1024) | k(1024) | v(1024)
#define ROWS  (BATCH*SEQ)  // 4096
#define LOG2E 1.44269504f

// ---------------- LayerNorm over the SEQUENCE axis (per (b,d)) ----------------
__global__ void ln_partial(const float* __restrict__ x,
                           float* __restrict__ psum, float* __restrict__ psq) {
    const int nc = blockIdx.x;   // 0..63
    const int b  = blockIdx.y;   // 0..1
    const int t  = threadIdx.x;  // 0..255
    const float* xp = x + ((size_t)b*SEQ + (size_t)nc*32)*DIMD;
    float s0=0,s1=0,s2=0,s3=0,q0=0,q1=0,q2=0,q3=0;
    for (int r=0; r<32; ++r) {
        const float* row = xp + (size_t)r*DIMD;
        float v0=row[t], v1=row[t+256], v2=row[t+512], v3=row[t+768];
        s0+=v0; q0+=v0*v0; s1+=v1; q1+=v1*v1;
        s2+=v2; q2+=v2*v2; s3+=v3; q3+=v3*v3;
    }
    float* ps = psum + ((size_t)b*64 + nc)*DIMD;
    float* pq = psq  + ((size_t)b*64 + nc)*DIMD;
    ps[t]=s0; ps[t+256]=s1; ps[t+512]=s2; ps[t+768]=s3;
    pq[t]=q0; pq[t+256]=q1; pq[t+512]=q2; pq[t+768]=q3;
}

__global__ void ln_finalize(const float* __restrict__ psum, const float* __restrict__ psq,
                            const float* __restrict__ g,
                            float* __restrict__ scale, float* __restrict__ shift) {
    const int d = blockIdx.x*256 + threadIdx.x;  // 0..1023
    const int b = blockIdx.y;
    float s=0.f, q=0.f;
    for (int nc=0; nc<64; ++nc) {
        s += psum[((size_t)b*64+nc)*DIMD + d];
        q += psq [((size_t)b*64+nc)*DIMD + d];
    }
    const float inv_n = 1.f/(float)SEQ;
    float mean = s*inv_n;
    float var  = q*inv_n - mean*mean;
    var = fmaxf(var, 1e-5f);
    scale[b*DIMD+d] = g[d]*rsqrtf(var);
    shift[b*DIMD+d] = mean;
}

__global__ void ln_apply(const float* __restrict__ x,
                         const float* __restrict__ scale, const float* __restrict__ shift,
                         bf16* __restrict__ xn) {
    size_t idx = ((size_t)blockIdx.x*256 + threadIdx.x)*4;
    int b = (int)(idx >> 21);          // SEQ*DIMD = 2^21
    int d = (int)(idx & (DIMD-1));
    f32x4 v  = *reinterpret_cast<const f32x4*>(x + idx);
    f32x4 sc = *reinterpret_cast<const f32x4*>(scale + (size_t)b*DIMD + d);
    f32x4 sh = *reinterpret_cast<const f32x4*>(shift + (size_t)b*DIMD + d);
    bf16x4 o;
    o.x = (bf16)((v.x - sh.x)*sc.x);
    o.y = (bf16)((v.y - sh.y)*sc.y);
    o.z = (bf16)((v.z - sh.z)*sc.z);
    o.w = (bf16)((v.w - sh.w)*sc.w);
    *reinterpret_cast<bf16x4*>(xn + idx) = o;
}

// ---------------- merged weight casts (Wq*qs, Wkv, Wo) ----------------
__global__ void castk_all(const float* __restrict__ Wq, const float* __restrict__ Wkv,
                          const float* __restrict__ Wo,
                          bf16* __restrict__ wqkv, bf16* __restrict__ wo, float qs) {
    int i = (blockIdx.x*256 + threadIdx.x)*4;   // 0 .. 4M-4
    f32x4 v; bf16* dst;
    if (i < 1048576)      { v = *reinterpret_cast<const f32x4*>(Wq + i);
                            v.x*=qs; v.y*=qs; v.z*=qs; v.w*=qs; dst = wqkv + i; }
    else if (i < 3145728) { v = *reinterpret_cast<const f32x4*>(Wkv + (i-1048576));
                            dst = wqkv + i; }
    else                  { v = *reinterpret_cast<const f32x4*>(Wo + (i-3145728));
                            dst = wo + (i-3145728); }
    bf16x4 o; o.x=(bf16)v.x; o.y=(bf16)v.y; o.z=(bf16)v.z; o.w=(bf16)v.w;
    *reinterpret_cast<bf16x4*>(dst) = o;
}

// ---------------- async global->LDS (16B, m97 pattern) ----------------
__device__ __forceinline__ void gload16(const void* g, void* l) {
    __builtin_amdgcn_global_load_lds(
        (const __attribute__((address_space(1))) unsigned int*)g,
        (__attribute__((address_space(3))) unsigned int*)l,
        16, 0, 0);
}

// ---------------- bt-GEMM (m97 structure): C[m][n] = sum_k A[m][k]*B[n][k] ----
__device__ inline void store_out(float* p, float v) { *p = v; }
__device__ inline void store_out(bf16*  p, float v) { *p = (bf16)v; }

template <typename OT>
__global__ __launch_bounds__(256, 2)
void gemm_bt(const bf16* __restrict__ A, const bf16* __restrict__ B,
             OT* __restrict__ C, int M, int N, int K) {
    __shared__ bf16 As[128*64];
    __shared__ bf16 Bs[128*64];
    const int t = threadIdx.x;
    const int wave = t >> 6, lane = t & 63;
    const int wr = wave >> 1, wc = wave & 1;
    const int m0 = blockIdx.y*128, n0 = blockIdx.x*128;
    const int lr = lane & 15, lg = lane >> 4;
    const int srow = wave*32 + (lane>>3);   // +8*i
    const int scol = (lane&7)*8;            // bf16 elems (16B)

    f32x4 acc[4][4];
    #pragma unroll
    for (int i=0;i<4;++i)
        #pragma unroll
        for (int j=0;j<4;++j) acc[i][j] = (f32x4){0.f,0.f,0.f,0.f};

    for (int k0=0; k0<K; k0+=64) {
        #pragma unroll
        for (int i=0;i<4;++i) {
            gload16(A + (size_t)(m0+srow+8*i)*K + k0 + scol, As + (srow+8*i)*64 + scol);
            gload16(B + (size_t)(n0+srow+8*i)*K + k0 + scol, Bs + (srow+8*i)*64 + scol);
        }
        __syncthreads();
        #pragma unroll
        for (int kk=0; kk<2; ++kk) {
            bf16x8 a[4], b[4];
            #pragma unroll
            for (int mi=0;mi<4;++mi)
                a[mi] = *reinterpret_cast<const bf16x8*>(As + (wr*64+mi*16+lr)*64 + kk*32+lg*8);
            #pragma unroll
            for (int ni=0;ni<4;++ni)
                b[ni] = *reinterpret_cast<const bf16x8*>(Bs + (wc*64+ni*16+lr)*64 + kk*32+lg*8);
            #pragma unroll
            for (int mi=0;mi<4;++mi)
                #pragma unroll
                for (int ni=0;ni<4;++ni)
                    acc[mi][ni] = __builtin_amdgcn_mfma_f32_16x16x32_bf16(a[mi], b[ni], acc[mi][ni], 0, 0, 0);
        }
        __syncthreads();
    }
    #pragma unroll
    for (int mi=0;mi<4;++mi)
        #pragma unroll
        for (int ni=0;ni<4;++ni)
            #pragma unroll
            for (int r=0;r<4;++r) {
                int row = m0 + wr*64 + mi*16 + lg*4 + r;
                int col = n0 + wc*64 + ni*16 + lr;
                store_out(&C[(size_t)row*N + col], acc[mi][ni][r]);
            }
}

// ---------------- V transpose: qkv V part -> vT[b][h][d][n] ----------------
__global__ __launch_bounds__(256)
void transpose_v(const bf16* __restrict__ qkv, bf16* __restrict__ vT) {
    __shared__ bf16 tile[64][72];
    const int nt = blockIdx.x, h = blockIdx.y, b = blockIdx.z;
    const int t = threadIdx.x;
    const bf16* src = qkv + ((size_t)(b*SEQ + nt*64))*QKVN + 2*INNER + h*64;
    #pragma unroll
    for (int i=0;i<2;++i) {
        int c = t + 256*i, row = c>>3, col = (c&7)*8;
        *reinterpret_cast<bf16x8*>(&tile[row][col]) =
            *reinterpret_cast<const bf16x8*>(src + (size_t)row*QKVN + col);
    }
    __syncthreads();
    bf16* dst = vT + ((size_t)(b*HEADS + h))*64*SEQ + nt*64;
    #pragma unroll
    for (int i=0;i<2;++i) {
        int c = t + 256*i, d = c>>3, n0 = (c&7)*8;
        bf16x8 v;
        #pragma unroll
        for (int j=0;j<8;++j) v[j] = tile[n0+j][d];
        *reinterpret_cast<bf16x8*>(dst + (size_t)d*SEQ + n0) = v;
    }
}

// ---------------- fused flash attention: hybrid staging ----------------------
// Block = (qt, h), 512 threads = 8 waves (waves 0-3 batch 0, 4-7 batch 1).
// K/V reg-staged ping-pong (R16-proven). Bias via global_load_lds: 3 LDS bufs,
// 2-tile lookahead, NO vmcnt drain — in-order vmcnt retirement + the compiler's
// automatic waits at the K/V ds_write commit guarantee bias(T+1) has landed
// (bias DMA for a tile is always issued BEFORE that tile's K/V reg loads;
// sched_barrier pins the order). Barrier stays lgkmcnt(0)-only.
// LDS: K/V 64KB + bias 3x32KB = 160KB exactly. 32x32 MFMA, in-reg P, exp2
// softmax w/ defer-max.

__device__ __forceinline__ unsigned pk2(float a, float b) {
    union { bf16 h[2]; unsigned u; } x;
    x.h[0] = (bf16)a; x.h[1] = (bf16)b;
    return x.u;
}

#define ATTN_BARRIER()                                         \
    __builtin_amdgcn_sched_barrier(0);                         \
    asm volatile("s_waitcnt lgkmcnt(0)" ::: "memory");         \
    __builtin_amdgcn_s_barrier();                              \
    __builtin_amdgcn_sched_barrier(0)

// bias DMA for tile TT into buffer BUF (4 x 16B per thread, pre-swizzled src)
#define STAGE_BIAS(BUF, TT)                                                      \
  {                                                                              \
    float* bdst_ = BsL + (size_t)(BUF)*8192 + t*4;                               \
    _Pragma("unroll")                                                            \
    for (int i_=0;i_<4;++i_)                                                     \
        gload16(bptr + (size_t)(32*i_)*SEQ + (TT)*64, bdst_ + i_*2048);          \
  }

#define ATTN_ITER(CUR, T)                                                          \
  {                                                                                \
    /* commit staged K/V tile T+1 (both batches) -> buf CUR^1 */                   \
    /* (compiler's vmcnt wait here also forces bias(T+1) retired: in-order) */     \
    if ((T)+1 < 32) {                                                              \
      *reinterpret_cast<bf16x8*>(&Ks[0][(CUR)^1][st_off])  = krA;                  \
      *reinterpret_cast<bf16x8*>(&Ks[1][(CUR)^1][st_off])  = krB;                  \
      *reinterpret_cast<bf16x8*>(&VTs[0][(CUR)^1][st_off]) = vrA;                  \
      *reinterpret_cast<bf16x8*>(&VTs[1][(CUR)^1][st_off]) = vrB;                  \
    }                                                                              \
    __builtin_amdgcn_sched_barrier(0);                                             \
    /* bias DMA for tile T+2 FIRST (order matters for the retirement chain) */     \
    if ((T)+2 < 32) STAGE_BIAS(biasWr, (T)+2);                                     \
    __builtin_amdgcn_sched_barrier(0);                                             \
    /* K/V reg prefetch for tile T+2 */                                            \
    if ((T)+2 < 32) {                                                              \
      krA = *reinterpret_cast<const bf16x8*>(kbase0 + (size_t)(((T)+2)*64+srow)*QKVN + scol);  \
      krB = *reinterpret_cast<const bf16x8*>(kbase1 + (size_t)(((T)+2)*64+srow)*QKVN + scol);  \
      vrA = *reinterpret_cast<const bf16x8*>(vtb0 + (size_t)srow*SEQ + ((T)+2)*64 + scol);     \
      vrB = *reinterpret_cast<const bf16x8*>(vtb1 + (size_t)srow*SEQ + ((T)+2)*64 + scol);     \
    }                                                                              \
    /* QK(T): S^T = mfma(K, Q), two 32-kv blocks */                                \
    f32x16 p0 = (f32x16)(0.0f), p1 = (f32x16)(0.0f);                               \
    __builtin_amdgcn_s_setprio(1);                                                 \
    _Pragma("unroll")                                                              \
    for (int s=0;s<4;++s) {                                                        \
      bf16x8 kf0 = *reinterpret_cast<const bf16x8*>(&myK[(CUR)*4096 + koff[0][s]]); \
      p0 = __builtin_amdgcn_mfma_f32_32x32x16_bf16(kf0, qf[s], p0, 0,0,0);         \
      bf16x8 kf1 = *reinterpret_cast<const bf16x8*>(&myK[(CUR)*4096 + koff[1][s]]); \
      p1 = __builtin_amdgcn_mfma_f32_32x32x16_bf16(kf1, qf[s], p1, 0,0,0);         \
    }                                                                              \
    __builtin_amdgcn_s_setprio(0);                                                 \
    /* bias(T) from LDS buf biasRd (2-way max, free) */                            \
    const float* bcur_ = BsL + (size_t)biasRd*8192;                                \
    f32x4 bb0[4], bb1[4];                                                          \
    _Pragma("unroll")                                                              \
    for (int rr=0;rr<4;++rr) {                                                     \
      bb0[rr] = *reinterpret_cast<const f32x4*>(&bcur_[brd[0][rr]]);               \
      bb1[rr] = *reinterpret_cast<const f32x4*>(&bcur_[brd[1][rr]]);               \
    }                                                                              \
    /* softmax: bias add (exp2 domain), in-lane tree, cross-half combine */        \
    float v0[16], v1[16];                                                          \
    _Pragma("unroll")                                                              \
    for (int r=0;r<16;++r) {                                                       \
      v0[r] = __builtin_fmaf(bb0[r>>2][r&3], LOG2E, p0[r]);                        \
      v1[r] = __builtin_fmaf(bb1[r>>2][r&3], LOG2E, p1[r]);                        \
    }                                                                              \
    float mx[8];                                                                   \
    _Pragma("unroll")                                                              \
    for (int i=0;i<8;++i)                                                          \
      mx[i] = fmaxf(fmaxf(v0[i], v0[i+8]), fmaxf(v1[i], v1[i+8]));                 \
    _Pragma("unroll")                                                              \
    for (int i=0;i<4;++i) mx[i] = fmaxf(mx[i], mx[i+4]);                           \
    float vmax = fmaxf(fmaxf(mx[0],mx[2]), fmaxf(mx[1],mx[3]));                    \
    vmax = fmaxf(vmax, __shfl_xor(vmax, 32));                                      \
    if (!__all(vmax <= m + 11.5f)) {                                               \
      float mnew = fmaxf(m, vmax);                                                 \
      float sc = __builtin_amdgcn_exp2f(m - mnew);                                 \
      m = mnew; l *= sc;                                                           \
      _Pragma("unroll")                                                            \
      for (int r=0;r<16;++r) {                                                     \
        float scr = __shfl(sc, (r&3)+8*(r>>2)+4*hi);                               \
        accO0[r] *= scr; accO1[r] *= scr;                                          \
      }                                                                            \
    }                                                                              \
    float e0[16], e1[16];                                                          \
    _Pragma("unroll")                                                              \
    for (int r=0;r<16;++r) {                                                       \
      e0[r] = __builtin_amdgcn_exp2f(v0[r] - m);                                   \
      e1[r] = __builtin_amdgcn_exp2f(v1[r] - m);                                   \
    }                                                                              \
    float sm[8];                                                                   \
    _Pragma("unroll")                                                              \
    for (int i=0;i<8;++i) sm[i] = (e0[i]+e0[i+8]) + (e1[i]+e1[i+8]);               \
    _Pragma("unroll")                                                              \
    for (int i=0;i<4;++i) sm[i] += sm[i+4];                                        \
    float rsum = (sm[0]+sm[2]) + (sm[1]+sm[3]);                                    \
    rsum += __shfl_xor(rsum, 32);                                                  \
    l += rsum;                                                                     \
    /* pack P to bf16 words: W[B2][rr][h] = kv pair (32B2+8rr+4hi+2h, +1) */       \
    unsigned W0[4][2], W1[4][2];                                                   \
    _Pragma("unroll")                                                              \
    for (int rr=0;rr<4;++rr) {                                                     \
      W0[rr][0] = pk2(e0[4*rr+0], e0[4*rr+1]);                                     \
      W0[rr][1] = pk2(e0[4*rr+2], e0[4*rr+3]);                                     \
      W1[rr][0] = pk2(e1[4*rr+0], e1[4*rr+1]);                                     \
      W1[rr][1] = pk2(e1[4*rr+2], e1[4*rr+3]);                                     \
    }                                                                              \
    /* build PV A-frags pa[s4]: kv = 16*s4 + 8*hi + e */                           \
    bf16x8 pa[4];                                                                  \
    _Pragma("unroll")                                                              \
    for (int s4=0;s4<4;++s4) {                                                     \
      unsigned u[4];                                                               \
      _Pragma("unroll")                                                            \
      for (int hh=0;hh<2;++hh) {                                                   \
        unsigned a0 = (s4>>1) ? W1[2*(s4&1)  ][hh] : W0[2*(s4&1)  ][hh];           \
        unsigned a1 = (s4>>1) ? W1[2*(s4&1)+1][hh] : W0[2*(s4&1)+1][hh];           \
        unsigned X = hi ? a0 : a1;                                                 \
        unsigned R = (unsigned)__shfl_xor((int)X, 32);                             \
        u[hh]   = hi ? R  : a0;                                                    \
        u[2+hh] = hi ? a1 : R;                                                     \
      }                                                                            \
      u32x4 uv = {u[0], u[1], u[2], u[3]};                                         \
      pa[s4] = __builtin_bit_cast(bf16x8, uv);                                     \
    }                                                                              \
    /* PV(T) */                                                                    \
    __builtin_amdgcn_s_setprio(1);                                                 \
    _Pragma("unroll")                                                              \
    for (int s4=0;s4<4;++s4) {                                                     \
      bf16x8 vfa = *reinterpret_cast<const bf16x8*>(&myV[(CUR)*4096 + voff[0][s4]]); \
      accO0 = __builtin_amdgcn_mfma_f32_32x32x16_bf16(pa[s4], vfa, accO0, 0,0,0);  \
      bf16x8 vfb = *reinterpret_cast<const bf16x8*>(&myV[(CUR)*4096 + voff[1][s4]]); \
      accO1 = __builtin_amdgcn_mfma_f32_32x32x16_bf16(pa[s4], vfb, accO1, 0,0,0);  \
    }                                                                              \
    __builtin_amdgcn_s_setprio(0);                                                 \
    ATTN_BARRIER();                                                                \
    biasRd = (biasRd==2) ? 0 : biasRd+1;                                           \
    biasWr = (biasWr==2) ? 0 : biasWr+1;                                           \
  }

__global__ __launch_bounds__(512, 1)
void attn_kernel(const bf16* __restrict__ qkv, const bf16* __restrict__ vTg,
                 const float* __restrict__ bias, bf16* __restrict__ oh) {
    __shared__ bf16 Ks[2][2][64*64];    // [batch][buf] 8KB tiles (32KB)
    __shared__ bf16 VTs[2][2][64*64];   // [batch][buf]          (32KB)
    __shared__ float BsLarr[3*128*64];  // 3 bias bufs [128 q][64 kv] (96KB)
    float* BsL = BsLarr;

    const int qt = blockIdx.x, h = blockIdx.y;
    const int t = threadIdx.x;
    const int w = t >> 6, lane = t & 63;
    const int wb = w >> 2;               // batch of this wave
    const int wq = w & 3;                // q-subtile within batch
    const int ql = lane & 31, hi = lane >> 5;
    const int q0 = qt*128;

    // swizzled LDS read offsets for K/V (elements), + CUR*4096
    int koff[2][4], voff[2][4];
    #pragma unroll
    for (int B2=0;B2<2;++B2)
        #pragma unroll
        for (int s=0;s<4;++s) {
            koff[B2][s] = (32*B2+ql)*64 + (((2*s+hi) ^ (ql&7))*8);
            voff[B2][s] = (32*B2+ql)*64 + (((2*s+hi) ^ (ql&7))*8);
        }
    bf16* myK = (bf16*)Ks[wb];
    bf16* myV = (bf16*)VTs[wb];

    // bias read offsets: LDS[row][x16] holds source granule x ^ (row&15)
    int brd[2][4];
    #pragma unroll
    for (int B2=0;B2<2;++B2)
        #pragma unroll
        for (int rr=0;rr<4;++rr)
            brd[B2][rr] = (wq*32+ql)*64 + (((8*B2+2*rr+hi) ^ (ql&15))*4);

    // K/V staging map: 512 threads cover one 64x64 tile (1 b128 each)
    const int srow = t>>3;               // 0..63
    const int scol = (t&7)*8;
    const int st_off = srow*64 + (((t&7) ^ (srow&7))*8);

    // Q fragments (prescaled 0.125*log2e): row q0+wq*32+ql, d = 16s+8hi+e
    const bf16* qrow = qkv + ((size_t)(wb*SEQ + q0 + wq*32 + ql))*QKVN + h*64 + hi*8;
    bf16x8 qf[4];
    #pragma unroll
    for (int s=0;s<4;++s)
        qf[s] = *reinterpret_cast<const bf16x8*>(qrow + 16*s);

    const bf16* kbase0 = qkv + INNER + h*64;
    const bf16* kbase1 = qkv + (size_t)SEQ*QKVN + INNER + h*64;
    const bf16* vtb0   = vTg + (size_t)h*64*SEQ;
    const bf16* vtb1   = vTg + (size_t)(HEADS + h)*64*SEQ;
    // bias DMA source (pre-swizzled): round i -> LDS row (t>>4)+32i, dest linear;
    // source granule (t&15)^((t>>4)&15) of row q0+(t>>4)+32i
    const float* bptr = bias + ((size_t)h*SEQ + (size_t)(q0 + (t>>4)))*SEQ
                              + (((t&15) ^ ((t>>4)&15))*4);

    bf16x8 krA, krB, vrA, vrB;
    int biasRd = 0, biasWr = 2;

    // prologue:
    // bias(0)->buf0, bias(1)->buf1 (DMA, issued FIRST)
    STAGE_BIAS(0, 0);
    STAGE_BIAS(1, 1);
    __builtin_amdgcn_sched_barrier(0);
    // K/V tile0 regs -> LDS buf0 (the reg waits force bias(0)/(1) retirement
    // transitively at the next ds_write-dependent point); tile1 -> regs
    *reinterpret_cast<bf16x8*>(&Ks[0][0][st_off]) =
        *reinterpret_cast<const bf16x8*>(kbase0 + (size_t)srow*QKVN + scol);
    *reinterpret_cast<bf16x8*>(&Ks[1][0][st_off]) =
        *reinterpret_cast<const bf16x8*>(kbase1 + (size_t)srow*QKVN + scol);
    *reinterpret_cast<bf16x8*>(&VTs[0][0][st_off]) =
        *reinterpret_cast<const bf16x8*>(vtb0 + (size_t)srow*SEQ + scol);
    *reinterpret_cast<bf16x8*>(&VTs[1][0][st_off]) =
        *reinterpret_cast<const bf16x8*>(vtb1 + (size_t)srow*SEQ + scol);
    krA = *reinterpret_cast<const bf16x8*>(kbase0 + (size_t)(64+srow)*QKVN + scol);
    krB = *reinterpret_cast<const bf16x8*>(kbase1 + (size_t)(64+srow)*QKVN + scol);
    vrA = *reinterpret_cast<const bf16x8*>(vtb0 + (size_t)srow*SEQ + 64 + scol);
    vrB = *reinterpret_cast<const bf16x8*>(vtb1 + (size_t)srow*SEQ + 64 + scol);
    // ensure bias(0) is in LDS before first read: drain all VMEM once (prologue only)
    __builtin_amdgcn_sched_barrier(0);
    asm volatile("s_waitcnt vmcnt(0) lgkmcnt(0)" ::: "memory");
    __builtin_amdgcn_s_barrier();
    __builtin_amdgcn_sched_barrier(0);

    float m = -__builtin_inff();
    float l = 0.f;
    f32x16 accO0 = (f32x16)(0.0f), accO1 = (f32x16)(0.0f);

    for (int t2 = 0; t2 < 32; t2 += 2) {
        ATTN_ITER(0, t2);
        ATTN_ITER(1, t2+1);
    }

    // epilogue: O /= l ; accO{dt}[r]: q = (r&3)+8*(r>>2)+4*hi, d = dt*32+ql
    float linv = 1.f/l;
    bf16* ob = oh + ((size_t)(wb*SEQ + q0 + wq*32))*INNER + h*64 + ql;
    #pragma unroll
    for (int r=0;r<16;++r) {
        int qoff = (r&3) + 8*(r>>2) + 4*hi;
        float li = __shfl(linv, qoff);
        ob[(size_t)qoff*INNER]      = (bf16)(accO0[r]*li);
        ob[(size_t)qoff*INNER + 32] = (bf16)(accO1[r]*li);
    }
}

// ---------------- host launcher ----------------
extern "C" void kernel_launch(void* const* d_in, const int* in_sizes, int n_in,
                              void* d_out, int out_size, void* d_ws, size_t ws_size,
                              hipStream_t stream) {
    const float* x    = (const float*)d_in[0];
    const float* bias = (const float*)d_in[1];
    const float* g    = (const float*)d_in[2];
    const float* Wq   = (const float*)d_in[3];
    const float* Wkv  = (const float*)d_in[4];
    const float* Wo   = (const float*)d_in[5];
    float* out = (float*)d_out;

    char* ws = (char*)d_ws;
    bf16*  xn    = (bf16*)(ws);                       //  8,388,608 B (dead after QKV gemm)
    bf16*  vT    = (bf16*)(ws);                       //  overlays xn
    bf16*  wqkv  = (bf16*)(ws + 8388608);             //  6,291,456 B
    bf16*  wo    = (bf16*)(ws + 14680064);            //  2,097,152 B
    bf16*  qkv   = (bf16*)(ws + 16777216);            // 25,165,824 B
    bf16*  oh    = (bf16*)(ws + 41943040);            //  8,388,608 B
    float* psum  = (float*)(ws + 50331648);           //    524,288 B
    float* psq   = (float*)(ws + 50855936);           //    524,288 B
    float* scale = (float*)(ws + 51380224);           //      8,192 B
    float* shift = (float*)(ws + 51388416);           //      8,192 B

    ln_partial <<<dim3(64,2), 256, 0, stream>>>(x, psum, psq);
    ln_finalize<<<dim3(4,2),  256, 0, stream>>>(psum, psq, g, scale, shift);
    ln_apply   <<<dim3(4096), 256, 0, stream>>>(x, scale, shift, xn);

    // merged weight casts: Wq prescaled by 0.125*log2e, Wkv, Wo
    castk_all<<<dim3(4096), 256, 0, stream>>>(Wq, Wkv, Wo, wqkv, wo, 0.125f*LOG2E);

    // QKV = xn @ [Wq;Wkv]^T : M=4096, N=3072, K=1024
    gemm_bt<bf16><<<dim3(24,32), 256, 0, stream>>>(xn, wqkv, qkv, ROWS, QKVN, DIMD);

    // V -> V^T (per (b,h): [2048 n][64 d] -> [64 d][2048 n]); vT overlays dead xn
    transpose_v<<<dim3(32,16,2), 256, 0, stream>>>(qkv, vT);

    // fused attention (dual-batch, reg-staged K/V + DMA bias 3-buf) -> oh
    attn_kernel<<<dim3(16,16), 512, 0, stream>>>(qkv, vT, bias, oh);

    // final = oh @ Wo^T : M=4096, N=1024, K=1024, fp32 out
    gemm_bt<float><<<dim3(8,32), 256, 0, stream>>>(oh, wo, out, ROWS, INNER, INNER);
}

// Round 19
// 171.868 us; speedup vs baseline: 1.1267x; 1.0877x over previous
//
#include <hip/hip_runtime.h>
#include <hip/hip_bf16.h>

typedef __bf16 bf16;
typedef __attribute__((ext_vector_type(8))) __bf16 bf16x8;
typedef __attribute__((ext_vector_type(4))) __bf16 bf16x4;
typedef __attribute__((ext_vector_type(4))) float f32x4;
typedef __attribute__((ext_vector_type(16))) float f32x16;
typedef __attribute__((ext_vector_type(4))) unsigned int u32x4;

#define DIMD  1024
#define SEQ   2048
#define BATCH 2
#define HEADS 16
#define INNER 1024
#define QKVN  3072   // q(1024) | k(1024) | v(1024)
#define ROWS  (BATCH*SEQ)  // 4096
#define LOG2E 1.44269504f

// ---------------- LayerNorm over the SEQUENCE axis (per (b,d)) ----------------
__global__ void ln_partial(const float* __restrict__ x,
                           float* __restrict__ psum, float* __restrict__ psq) {
    const int nc = blockIdx.x;   // 0..63
    const int b  = blockIdx.y;   // 0..1
    const int t  = threadIdx.x;  // 0..255
    const float* xp = x + ((size_t)b*SEQ + (size_t)nc*32)*DIMD;
    float s0=0,s1=0,s2=0,s3=0,q0=0,q1=0,q2=0,q3=0;
    for (int r=0; r<32; ++r) {
        const float* row = xp + (size_t)r*DIMD;
        float v0=row[t], v1=row[t+256], v2=row[t+512], v3=row[t+768];
        s0+=v0; q0+=v0*v0; s1+=v1; q1+=v1*v1;
        s2+=v2; q2+=v2*v2; s3+=v3; q3+=v3*v3;
    }
    float* ps = psum + ((size_t)b*64 + nc)*DIMD;
    float* pq = psq  + ((size_t)b*64 + nc)*DIMD;
    ps[t]=s0; ps[t+256]=s1; ps[t+512]=s2; ps[t+768]=s3;
    pq[t]=q0; pq[t+256]=q1; pq[t+512]=q2; pq[t+768]=q3;
}

__global__ void ln_finalize(const float* __restrict__ psum, const float* __restrict__ psq,
                            const float* __restrict__ g,
                            float* __restrict__ scale, float* __restrict__ shift) {
    const int d = blockIdx.x*256 + threadIdx.x;  // 0..1023
    const int b = blockIdx.y;
    float s=0.f, q=0.f;
    for (int nc=0; nc<64; ++nc) {
        s += psum[((size_t)b*64+nc)*DIMD + d];
        q += psq [((size_t)b*64+nc)*DIMD + d];
    }
    const float inv_n = 1.f/(float)SEQ;
    float mean = s*inv_n;
    float var  = q*inv_n - mean*mean;
    var = fmaxf(var, 1e-5f);
    scale[b*DIMD+d] = g[d]*rsqrtf(var);
    shift[b*DIMD+d] = mean;
}

__global__ void ln_apply(const float* __restrict__ x,
                         const float* __restrict__ scale, const float* __restrict__ shift,
                         bf16* __restrict__ xn) {
    size_t idx = ((size_t)blockIdx.x*256 + threadIdx.x)*4;
    int b = (int)(idx >> 21);          // SEQ*DIMD = 2^21
    int d = (int)(idx & (DIMD-1));
    f32x4 v  = *reinterpret_cast<const f32x4*>(x + idx);
    f32x4 sc = *reinterpret_cast<const f32x4*>(scale + (size_t)b*DIMD + d);
    f32x4 sh = *reinterpret_cast<const f32x4*>(shift + (size_t)b*DIMD + d);
    bf16x4 o;
    o.x = (bf16)((v.x - sh.x)*sc.x);
    o.y = (bf16)((v.y - sh.y)*sc.y);
    o.z = (bf16)((v.z - sh.z)*sc.z);
    o.w = (bf16)((v.w - sh.w)*sc.w);
    *reinterpret_cast<bf16x4*>(xn + idx) = o;
}

// ---------------- merged weight casts (Wq*qs, Wkv, Wo) ----------------
__global__ void castk_all(const float* __restrict__ Wq, const float* __restrict__ Wkv,
                          const float* __restrict__ Wo,
                          bf16* __restrict__ wqkv, bf16* __restrict__ wo, float qs) {
    int i = (blockIdx.x*256 + threadIdx.x)*4;   // 0 .. 4M-4
    f32x4 v; bf16* dst;
    if (i < 1048576)      { v = *reinterpret_cast<const f32x4*>(Wq + i);
                            v.x*=qs; v.y*=qs; v.z*=qs; v.w*=qs; dst = wqkv + i; }
    else if (i < 3145728) { v = *reinterpret_cast<const f32x4*>(Wkv + (i-1048576));
                            dst = wqkv + i; }
    else                  { v = *reinterpret_cast<const f32x4*>(Wo + (i-3145728));
                            dst = wo + (i-3145728); }
    bf16x4 o; o.x=(bf16)v.x; o.y=(bf16)v.y; o.z=(bf16)v.z; o.w=(bf16)v.w;
    *reinterpret_cast<bf16x4*>(dst) = o;
}

// ---------------- async global->LDS (16B, m97 pattern) ----------------
__device__ __forceinline__ void gload16(const void* g, void* l) {
    __builtin_amdgcn_global_load_lds(
        (const __attribute__((address_space(1))) unsigned int*)g,
        (__attribute__((address_space(3))) unsigned int*)l,
        16, 0, 0);
}

// ---------------- bt-GEMM (m97 structure): C[m][n] = sum_k A[m][k]*B[n][k] ----
// FUSE_VT: N-blocks with n0 >= 2048 (the V part of the QKV GEMM) are stored
// TRANSPOSED into vT[b][h][d][n] instead of C — eliminates transpose_v.
__device__ inline void store_out(float* p, float v) { *p = v; }
__device__ inline void store_out(bf16*  p, float v) { *p = (bf16)v; }

template <typename OT, bool FUSE_VT>
__global__ __launch_bounds__(256, 2)
void gemm_bt(const bf16* __restrict__ A, const bf16* __restrict__ B,
             OT* __restrict__ C, bf16* __restrict__ vTout, int M, int N, int K) {
    __shared__ bf16 As[128*64];
    __shared__ bf16 Bs[128*64];
    const int t = threadIdx.x;
    const int wave = t >> 6, lane = t & 63;
    const int wr = wave >> 1, wc = wave & 1;
    const int m0 = blockIdx.y*128, n0 = blockIdx.x*128;
    const int lr = lane & 15, lg = lane >> 4;
    const int srow = wave*32 + (lane>>3);   // +8*i
    const int scol = (lane&7)*8;            // bf16 elems (16B)

    f32x4 acc[4][4];
    #pragma unroll
    for (int i=0;i<4;++i)
        #pragma unroll
        for (int j=0;j<4;++j) acc[i][j] = (f32x4){0.f,0.f,0.f,0.f};

    for (int k0=0; k0<K; k0+=64) {
        #pragma unroll
        for (int i=0;i<4;++i) {
            gload16(A + (size_t)(m0+srow+8*i)*K + k0 + scol, As + (srow+8*i)*64 + scol);
            gload16(B + (size_t)(n0+srow+8*i)*K + k0 + scol, Bs + (srow+8*i)*64 + scol);
        }
        __syncthreads();
        #pragma unroll
        for (int kk=0; kk<2; ++kk) {
            bf16x8 a[4], b[4];
            #pragma unroll
            for (int mi=0;mi<4;++mi)
                a[mi] = *reinterpret_cast<const bf16x8*>(As + (wr*64+mi*16+lr)*64 + kk*32+lg*8);
            #pragma unroll
            for (int ni=0;ni<4;++ni)
                b[ni] = *reinterpret_cast<const bf16x8*>(Bs + (wc*64+ni*16+lr)*64 + kk*32+lg*8);
            #pragma unroll
            for (int mi=0;mi<4;++mi)
                #pragma unroll
                for (int ni=0;ni<4;++ni)
                    acc[mi][ni] = __builtin_amdgcn_mfma_f32_16x16x32_bf16(a[mi], b[ni], acc[mi][ni], 0, 0, 0);
        }
        __syncthreads();
    }
    if (FUSE_VT && n0 >= 2*INNER) {
        // V block: store transposed. row = m0+wr*64+mi*16+lg*4+r (n within batch),
        // col = n0+wc*64+ni*16+lr -> (h,d). 4 r-values are consecutive n -> bf16x4.
        #pragma unroll
        for (int mi=0;mi<4;++mi)
            #pragma unroll
            for (int ni=0;ni<4;++ni) {
                int row0 = m0 + wr*64 + mi*16 + lg*4;
                int col  = n0 + wc*64 + ni*16 + lr;
                int vcol = col - 2*INNER;
                int bb = row0 >> 11, nn = row0 & (SEQ-1);
                size_t vrow = (size_t)(bb*HEADS + (vcol>>6))*64 + (vcol&63);
                bf16x4 pk;
                pk[0]=(bf16)acc[mi][ni][0]; pk[1]=(bf16)acc[mi][ni][1];
                pk[2]=(bf16)acc[mi][ni][2]; pk[3]=(bf16)acc[mi][ni][3];
                *reinterpret_cast<bf16x4*>(vTout + vrow*SEQ + nn) = pk;
            }
    } else {
        #pragma unroll
        for (int mi=0;mi<4;++mi)
            #pragma unroll
            for (int ni=0;ni<4;++ni)
                #pragma unroll
                for (int r=0;r<4;++r) {
                    int row = m0 + wr*64 + mi*16 + lg*4 + r;
                    int col = n0 + wc*64 + ni*16 + lr;
                    store_out(&C[(size_t)row*N + col], acc[mi][ni][r]);
                }
    }
}

// ---------------- fused flash attention: dual-batch, bias-once via LDS -------
// (R16 exact — best measured variant.)
// Block = (qt, h), 512 threads = 8 waves (waves 0-3 batch 0, 4-7 batch 1).
// Bias loaded ONCE per block (coalesced, 4x f32x4/thread), double-buffered in
// block-shared swizzled LDS [128 q][64 kv]; both batch halves read it from LDS.
// K/V per-batch ping-pong LDS, single raw barrier/iter, 32x32 MFMA, in-reg P,
// exp2 softmax w/ defer-max.

__device__ __forceinline__ unsigned pk2(float a, float b) {
    union { bf16 h[2]; unsigned u; } x;
    x.h[0] = (bf16)a; x.h[1] = (bf16)b;
    return x.u;
}

#define ATTN_BARRIER()                                         \
    __builtin_amdgcn_sched_barrier(0);                         \
    asm volatile("s_waitcnt lgkmcnt(0)" ::: "memory");         \
    __builtin_amdgcn_s_barrier();                              \
    __builtin_amdgcn_sched_barrier(0)

#define ATTN_ITER(CUR, T)                                                          \
  {                                                                                \
    /* commit staged tiles T+1 -> buf CUR^1: K/V (both batches) + bias */          \
    if ((T)+1 < 32) {                                                              \
      *reinterpret_cast<bf16x8*>(&Ks[0][(CUR)^1][st_off])  = krA;                  \
      *reinterpret_cast<bf16x8*>(&Ks[1][(CUR)^1][st_off])  = krB;                  \
      *reinterpret_cast<bf16x8*>(&VTs[0][(CUR)^1][st_off]) = vrA;                  \
      *reinterpret_cast<bf16x8*>(&VTs[1][(CUR)^1][st_off]) = vrB;                  \
      _Pragma("unroll")                                                            \
      for (int i=0;i<4;++i)                                                        \
        *reinterpret_cast<f32x4*>(&BsL[(CUR)^1][bst[i]]) = breg[i];                \
    }                                                                              \
    /* prefetch tiles T+2 into regs (in flight across barrier) */                  \
    if ((T)+2 < 32) {                                                              \
      krA = *reinterpret_cast<const bf16x8*>(kbase0 + (size_t)(((T)+2)*64+srow)*QKVN + scol);  \
      krB = *reinterpret_cast<const bf16x8*>(kbase1 + (size_t)(((T)+2)*64+srow)*QKVN + scol);  \
      vrA = *reinterpret_cast<const bf16x8*>(vtb0 + (size_t)srow*SEQ + ((T)+2)*64 + scol);     \
      vrB = *reinterpret_cast<const bf16x8*>(vtb1 + (size_t)srow*SEQ + ((T)+2)*64 + scol);     \
      _Pragma("unroll")                                                            \
      for (int i=0;i<4;++i)                                                        \
        breg[i] = *reinterpret_cast<const f32x4*>(bgl + (size_t)(32*i)*SEQ + ((T)+2)*64);      \
    }                                                                              \
    /* QK(T): S^T = mfma(K, Q), two 32-kv blocks */                                \
    f32x16 p0 = (f32x16)(0.0f), p1 = (f32x16)(0.0f);                               \
    __builtin_amdgcn_s_setprio(1);                                                 \
    _Pragma("unroll")                                                              \
    for (int s=0;s<4;++s) {                                                        \
      bf16x8 kf0 = *reinterpret_cast<const bf16x8*>(&myK[(CUR)*4096 + koff[0][s]]); \
      p0 = __builtin_amdgcn_mfma_f32_32x32x16_bf16(kf0, qf[s], p0, 0,0,0);         \
      bf16x8 kf1 = *reinterpret_cast<const bf16x8*>(&myK[(CUR)*4096 + koff[1][s]]); \
      p1 = __builtin_amdgcn_mfma_f32_32x32x16_bf16(kf1, qf[s], p1, 0,0,0);         \
    }                                                                              \
    __builtin_amdgcn_s_setprio(0);                                                 \
    /* bias(T) from block-shared LDS (2-way max, free) */                          \
    f32x4 bb0[4], bb1[4];                                                          \
    _Pragma("unroll")                                                              \
    for (int rr=0;rr<4;++rr) {                                                     \
      bb0[rr] = *reinterpret_cast<const f32x4*>(&BsL[CUR][brd[0][rr]]);            \
      bb1[rr] = *reinterpret_cast<const f32x4*>(&BsL[CUR][brd[1][rr]]);            \
    }                                                                              \
    /* softmax: bias add (exp2 domain), in-lane tree, cross-half combine */        \
    float v0[16], v1[16];                                                          \
    _Pragma("unroll")                                                              \
    for (int r=0;r<16;++r) {                                                       \
      v0[r] = __builtin_fmaf(bb0[r>>2][r&3], LOG2E, p0[r]);                        \
      v1[r] = __builtin_fmaf(bb1[r>>2][r&3], LOG2E, p1[r]);                        \
    }                                                                              \
    float mx[8];                                                                   \
    _Pragma("unroll")                                                              \
    for (int i=0;i<8;++i)                                                          \
      mx[i] = fmaxf(fmaxf(v0[i], v0[i+8]), fmaxf(v1[i], v1[i+8]));                 \
    _Pragma("unroll")                                                              \
    for (int i=0;i<4;++i) mx[i] = fmaxf(mx[i], mx[i+4]);                           \
    float vmax = fmaxf(fmaxf(mx[0],mx[2]), fmaxf(mx[1],mx[3]));                    \
    vmax = fmaxf(vmax, __shfl_xor(vmax, 32));                                      \
    if (!__all(vmax <= m + 11.5f)) {                                               \
      float mnew = fmaxf(m, vmax);                                                 \
      float sc = __builtin_amdgcn_exp2f(m - mnew);                                 \
      m = mnew; l *= sc;                                                           \
      _Pragma("unroll")                                                            \
      for (int r=0;r<16;++r) {                                                     \
        float scr = __shfl(sc, (r&3)+8*(r>>2)+4*hi);                               \
        accO0[r] *= scr; accO1[r] *= scr;                                          \
      }                                                                            \
    }                                                                              \
    float e0[16], e1[16];                                                          \
    _Pragma("unroll")                                                              \
    for (int r=0;r<16;++r) {                                                       \
      e0[r] = __builtin_amdgcn_exp2f(v0[r] - m);                                   \
      e1[r] = __builtin_amdgcn_exp2f(v1[r] - m);                                   \
    }                                                                              \
    float sm[8];                                                                   \
    _Pragma("unroll")                                                              \
    for (int i=0;i<8;++i) sm[i] = (e0[i]+e0[i+8]) + (e1[i]+e1[i+8]);               \
    _Pragma("unroll")                                                              \
    for (int i=0;i<4;++i) sm[i] += sm[i+4];                                        \
    float rsum = (sm[0]+sm[2]) + (sm[1]+sm[3]);                                    \
    rsum += __shfl_xor(rsum, 32);                                                  \
    l += rsum;                                                                     \
    /* pack P to bf16 words: W[B2][rr][h] = kv pair (32B2+8rr+4hi+2h, +1) */       \
    unsigned W0[4][2], W1[4][2];                                                   \
    _Pragma("unroll")                                                              \
    for (int rr=0;rr<4;++rr) {                                                     \
      W0[rr][0] = pk2(e0[4*rr+0], e0[4*rr+1]);                                     \
      W0[rr][1] = pk2(e0[4*rr+2], e0[4*rr+3]);                                     \
      W1[rr][0] = pk2(e1[4*rr+0], e1[4*rr+1]);                                     \
      W1[rr][1] = pk2(e1[4*rr+2], e1[4*rr+3]);                                     \
    }                                                                              \
    /* build PV A-frags pa[s4]: kv = 16*s4 + 8*hi + e */                           \
    bf16x8 pa[4];                                                                  \
    _Pragma("unroll")                                                              \
    for (int s4=0;s4<4;++s4) {                                                     \
      unsigned u[4];                                                               \
      _Pragma("unroll")                                                            \
      for (int hh=0;hh<2;++hh) {                                                   \
        unsigned a0 = (s4>>1) ? W1[2*(s4&1)  ][hh] : W0[2*(s4&1)  ][hh];           \
        unsigned a1 = (s4>>1) ? W1[2*(s4&1)+1][hh] : W0[2*(s4&1)+1][hh];           \
        unsigned X = hi ? a0 : a1;                                                 \
        unsigned R = (unsigned)__shfl_xor((int)X, 32);                             \
        u[hh]   = hi ? R  : a0;                                                    \
        u[2+hh] = hi ? a1 : R;                                                     \
      }                                                                            \
      u32x4 uv = {u[0], u[1], u[2], u[3]};                                         \
      pa[s4] = __builtin_bit_cast(bf16x8, uv);                                     \
    }                                                                              \
    /* PV(T) */                                                                    \
    __builtin_amdgcn_s_setprio(1);                                                 \
    _Pragma("unroll")                                                              \
    for (int s4=0;s4<4;++s4) {                                                     \
      bf16x8 vfa = *reinterpret_cast<const bf16x8*>(&myV[(CUR)*4096 + voff[0][s4]]); \
      accO0 = __builtin_amdgcn_mfma_f32_32x32x16_bf16(pa[s4], vfa, accO0, 0,0,0);  \
      bf16x8 vfb = *reinterpret_cast<const bf16x8*>(&myV[(CUR)*4096 + voff[1][s4]]); \
      accO1 = __builtin_amdgcn_mfma_f32_32x32x16_bf16(pa[s4], vfb, accO1, 0,0,0);  \
    }                                                                              \
    __builtin_amdgcn_s_setprio(0);                                                 \
    ATTN_BARRIER();                                                                \
  }

__global__ __launch_bounds__(512, 1)
void attn_kernel(const bf16* __restrict__ qkv, const bf16* __restrict__ vTg,
                 const float* __restrict__ bias, bf16* __restrict__ oh) {
    __shared__ bf16 Ks[2][2][64*64];    // [batch][buf] 8KB tiles
    __shared__ bf16 VTs[2][2][64*64];   // [batch][buf]
    __shared__ float BsL[2][128*64];    // [buf][q 0..127][kv 0..63] swizzled (64KB)

    const int qt = blockIdx.x, h = blockIdx.y;
    const int t = threadIdx.x;
    const int w = t >> 6, lane = t & 63;
    const int wb = w >> 2;               // batch of this wave
    const int wq = w & 3;                // q-subtile within batch
    const int ql = lane & 31, hi = lane >> 5;
    const int q0 = qt*128;

    // swizzled LDS read offsets for K/V (elements), + CUR*4096
    int koff[2][4], voff[2][4];
    #pragma unroll
    for (int B2=0;B2<2;++B2)
        #pragma unroll
        for (int s=0;s<4;++s) {
            koff[B2][s] = (32*B2+ql)*64 + (((2*s+hi) ^ (ql&7))*8);
            voff[B2][s] = (32*B2+ql)*64 + (((2*s+hi) ^ (ql&7))*8);
        }
    bf16* myK = (bf16*)Ks[wb];
    bf16* myV = (bf16*)VTs[wb];

    // bias LDS offsets: write (4 rounds, 32 rows each), read (per-lane row)
    int bst[4];
    {
        int rlow = t>>4;                        // 0..31
        int swg  = ((t&15) ^ (rlow&15))*4;      // 16B-granule XOR-16 swizzle
        #pragma unroll
        for (int i=0;i<4;++i)
            bst[i] = (32*i + rlow)*64 + swg;
    }
    int brd[2][4];
    #pragma unroll
    for (int B2=0;B2<2;++B2)
        #pragma unroll
        for (int rr=0;rr<4;++rr)
            brd[B2][rr] = (wq*32+ql)*64 + (((8*B2+2*rr+hi) ^ (ql&15))*4);

    // K/V staging map: 512 threads cover one 64x64 tile (1 b128 each)
    const int srow = t>>3;               // 0..63
    const int scol = (t&7)*8;
    const int st_off = srow*64 + (((t&7) ^ (srow&7))*8);

    // Q fragments (prescaled 0.125*log2e): row q0+wq*32+ql, d = 16s+8hi+e
    const bf16* qrow = qkv + ((size_t)(wb*SEQ + q0 + wq*32 + ql))*QKVN + h*64 + hi*8;
    bf16x8 qf[4];
    #pragma unroll
    for (int s=0;s<4;++s)
        qf[s] = *reinterpret_cast<const bf16x8*>(qrow + 16*s);

    const bf16* kbase0 = qkv + INNER + h*64;
    const bf16* kbase1 = qkv + (size_t)SEQ*QKVN + INNER + h*64;
    const bf16* vtb0   = vTg + (size_t)h*64*SEQ;
    const bf16* vtb1   = vTg + (size_t)(HEADS + h)*64*SEQ;
    // coalesced bias base: thread t covers row q0 + 32*i + (t>>4), cols 4*(t&15)..+3
    const float* bgl = bias + ((size_t)h*SEQ + (size_t)(q0 + (t>>4)))*SEQ + 4*(t&15);

    bf16x8 krA, krB, vrA, vrB;
    f32x4 breg[4];

    // prologue: K/V tile0 (both batches) -> buf0; bias(0) -> BsL[0];
    // regs: K/V tile1, bias(1)
    *reinterpret_cast<bf16x8*>(&Ks[0][0][st_off]) =
        *reinterpret_cast<const bf16x8*>(kbase0 + (size_t)srow*QKVN + scol);
    *reinterpret_cast<bf16x8*>(&Ks[1][0][st_off]) =
        *reinterpret_cast<const bf16x8*>(kbase1 + (size_t)srow*QKVN + scol);
    *reinterpret_cast<bf16x8*>(&VTs[0][0][st_off]) =
        *reinterpret_cast<const bf16x8*>(vtb0 + (size_t)srow*SEQ + scol);
    *reinterpret_cast<bf16x8*>(&VTs[1][0][st_off]) =
        *reinterpret_cast<const bf16x8*>(vtb1 + (size_t)srow*SEQ + scol);
    #pragma unroll
    for (int i=0;i<4;++i)
        breg[i] = *reinterpret_cast<const f32x4*>(bgl + (size_t)(32*i)*SEQ);
    #pragma unroll
    for (int i=0;i<4;++i)
        *reinterpret_cast<f32x4*>(&BsL[0][bst[i]]) = breg[i];
    krA = *reinterpret_cast<const bf16x8*>(kbase0 + (size_t)(64+srow)*QKVN + scol);
    krB = *reinterpret_cast<const bf16x8*>(kbase1 + (size_t)(64+srow)*QKVN + scol);
    vrA = *reinterpret_cast<const bf16x8*>(vtb0 + (size_t)srow*SEQ + 64 + scol);
    vrB = *reinterpret_cast<const bf16x8*>(vtb1 + (size_t)srow*SEQ + 64 + scol);
    #pragma unroll
    for (int i=0;i<4;++i)
        breg[i] = *reinterpret_cast<const f32x4*>(bgl + (size_t)(32*i)*SEQ + 64);
    ATTN_BARRIER();

    float m = -__builtin_inff();
    float l = 0.f;
    f32x16 accO0 = (f32x16)(0.0f), accO1 = (f32x16)(0.0f);

    for (int t2 = 0; t2 < 32; t2 += 2) {
        ATTN_ITER(0, t2);
        ATTN_ITER(1, t2+1);
    }

    // epilogue: O /= l ; accO{dt}[r]: q = (r&3)+8*(r>>2)+4*hi, d = dt*32+ql
    float linv = 1.f/l;
    bf16* ob = oh + ((size_t)(wb*SEQ + q0 + wq*32))*INNER + h*64 + ql;
    #pragma unroll
    for (int r=0;r<16;++r) {
        int qoff = (r&3) + 8*(r>>2) + 4*hi;
        float li = __shfl(linv, qoff);
        ob[(size_t)qoff*INNER]      = (bf16)(accO0[r]*li);
        ob[(size_t)qoff*INNER + 32] = (bf16)(accO1[r]*li);
    }
}

// ---------------- host launcher ----------------
extern "C" void kernel_launch(void* const* d_in, const int* in_sizes, int n_in,
                              void* d_out, int out_size, void* d_ws, size_t ws_size,
                              hipStream_t stream) {
    const float* x    = (const float*)d_in[0];
    const float* bias = (const float*)d_in[1];
    const float* g    = (const float*)d_in[2];
    const float* Wq   = (const float*)d_in[3];
    const float* Wkv  = (const float*)d_in[4];
    const float* Wo   = (const float*)d_in[5];
    float* out = (float*)d_out;

    char* ws = (char*)d_ws;
    bf16*  xn    = (bf16*)(ws);                       //  8,388,608 B (dead after QKV gemm)
    bf16*  vT    = (bf16*)(ws + 8388608);             //  8,388,608 B (written by QKV gemm)
    bf16*  wqkv  = (bf16*)(ws + 16777216);            //  6,291,456 B
    bf16*  wo    = (bf16*)(ws + 23068672);            //  2,097,152 B
    bf16*  qkv   = (bf16*)(ws + 25165824);            // 25,165,824 B
    bf16*  oh    = (bf16*)(ws + 50331648);            //  8,388,608 B
    float* psum  = (float*)(ws + 58720256);           //    524,288 B
    float* psq   = (float*)(ws + 59244544);           //    524,288 B
    float* scale = (float*)(ws + 59768832);           //      8,192 B
    float* shift = (float*)(ws + 59777024);           //      8,192 B

    ln_partial <<<dim3(64,2), 256, 0, stream>>>(x, psum, psq);
    ln_finalize<<<dim3(4,2),  256, 0, stream>>>(psum, psq, g, scale, shift);
    ln_apply   <<<dim3(4096), 256, 0, stream>>>(x, scale, shift, xn);

    // merged weight casts: Wq prescaled by 0.125*log2e, Wkv, Wo
    castk_all<<<dim3(4096), 256, 0, stream>>>(Wq, Wkv, Wo, wqkv, wo, 0.125f*LOG2E);

    // QKV = xn @ [Wq;Wkv]^T : M=4096, N=3072, K=1024.
    // V-columns (n0>=2048) are stored DIRECTLY TRANSPOSED into vT.
    gemm_bt<bf16,true><<<dim3(24,32), 256, 0, stream>>>(xn, wqkv, qkv, vT, ROWS, QKVN, DIMD);

    // fused attention (dual-batch, bias loaded once per block via LDS) -> oh
    attn_kernel<<<dim3(16,16), 512, 0, stream>>>(qkv, vT, bias, oh);

    // final = oh @ Wo^T : M=4096, N=1024, K=1024, fp32 out
    gemm_bt<float,false><<<dim3(8,32), 256, 0, stream>>>(oh, wo, out, nullptr, ROWS, INNER, INNER);
}